// Round 8
// baseline (724.920 us; speedup 1.0000x reference)
//
#include <hip/hip_runtime.h>
#include <hip/hip_fp16.h>

// GraphEncoder: 3x GraphConv(norm='both'), DIM=64, fixed graph.
// R24 DIAGNOSTIC (keeps R23 code, best 236.6us): each preproc kernel body
// wrapped in an idempotent in-kernel REP loop (opaque-zero asm defeats
// load hoisting) so each dispatch inflates past the ~44us harness fills and
// lands in the rocprof top-5 -> per-kernel preproc timings in one round.
// Known: layers = 94us total (R21). Unknown: split of remaining ~142us
// across {edge_hist, part_scan, part_scatter, bucket_fused, oh2p, gaps}.
// Divide reported dur by REP: EH/8, SCAN/20, SCAT/8, BF/8, OH/8.
// Next round reverts the REP loops and attacks the measured fat.

#define N_NODES 65536
#define N_EDGES 1048576
#define DIM 64

#define CHUNKS 256
#define EPC (N_EDGES / CHUNKS)        // 4096 edges per scatter chunk
#define HB 128                        // edge_hist blocks (2 chunks each)
#define OH_WORDS 16384                // 65536 nodes packed 4-per-word (64KB)

#define EH_REP 8
#define SCAN_REP 20
#define SCAT_REP 8
#define BF_REP 8
#define OH_REP 8

struct alignas(8) h4 { __half2 a, b; };   // 4 halves = 8 B

// --- one pass over edges: dst partition hist + packed src hist + zero rows ---
__global__ void edge_hist(const int* __restrict__ src, const int* __restrict__ dst,
                          int* __restrict__ block_hist, unsigned* __restrict__ partial,
                          uint2* __restrict__ zeroA, uint2* __restrict__ zeroB) {
    __shared__ unsigned h[OH_WORDS];  // 64 KB: src histogram, 8-bit x4 packed
    __shared__ int bh[2][256];
    int t = threadIdx.x;
    int j = blockIdx.x;               // 0..127
    #pragma unroll 1
    for (int rep = 0; rep < EH_REP; rep++) {
        int zero = 0; asm volatile("" : "+v"(zero));
        for (int i = t; i < OH_WORDS; i += 256) h[i] = 0;
        bh[0][t] = 0; bh[1][t] = 0;
        __syncthreads();
        if (j == 0) {                 // zero row (row N_NODES, 128 B each table)
            if (t < 16) zeroA[t] = make_uint2(0u, 0u);
            else if (t < 32) zeroB[t - 16] = make_uint2(0u, 0u);
        }
        int base = j * (2 * EPC) + zero;
        for (int i = t; i < 2 * EPC; i += 256) {
            int s = src[base + i];
            int d = dst[base + i];
            atomicAdd(&h[s >> 2], 1u << ((s & 3) * 8));
            atomicAdd(&bh[i >> 12][d >> 8], 1);
        }
        __syncthreads();
        unsigned* dp = partial + (size_t)j * OH_WORDS + zero;
        for (int i = t; i < OH_WORDS; i += 256) dp[i] = h[i];
        block_hist[t * CHUNKS + 2 * j + zero]     = bh[0][t];
        block_hist[t * CHUNKS + 2 * j + 1 + zero] = bh[1][t];
        __syncthreads();
    }
}

// --- exclusive scan of 65536 (bucket-major [bucket][chunk]) ---
__global__ void part_scan(const int* __restrict__ bh, int* __restrict__ so) {
    __shared__ int s[1024];
    int t = threadIdx.x;
    #pragma unroll 1
    for (int rep = 0; rep < SCAN_REP; rep++) {
        int zero = 0; asm volatile("" : "+v"(zero));
        const int4* b4 = (const int4*)(bh + t * 64 + zero);
        int4 v[16];
        int sum = 0;
        #pragma unroll
        for (int i = 0; i < 16; i++) {
            v[i] = b4[i];
            sum += v[i].x + v[i].y + v[i].z + v[i].w;
        }
        s[t] = sum;
        __syncthreads();
        for (int off = 1; off < 1024; off <<= 1) {
            int u = (t >= off) ? s[t - off] : 0;
            __syncthreads();
            s[t] += u;
            __syncthreads();
        }
        int run = s[t] - sum;
        int* o = so + t * 64 + zero;
        #pragma unroll
        for (int i = 0; i < 16; i++) {
            o[4 * i + 0] = run; run += v[i].x;
            o[4 * i + 1] = run; run += v[i].y;
            o[4 * i + 2] = run; run += v[i].z;
            o[4 * i + 3] = run; run += v[i].w;
        }
        __syncthreads();
    }
}

// --- scatter into bucket order, COALESCED: block-local counting sort ---
__global__ void part_scatter(const int* __restrict__ src, const int* __restrict__ dst,
                             const int* __restrict__ so, int* __restrict__ bpack) {
    __shared__ int hist[256], sc[256], off[256], cur[256], gbase[256];
    __shared__ int sorted[EPC];                 // 16 KB, bucket-ordered edges
    __shared__ unsigned char pos2b[EPC];        // 4 KB, position -> bucket
    int t = threadIdx.x;
    int j = blockIdx.x;
    #pragma unroll 1
    for (int rep = 0; rep < SCAT_REP; rep++) {
        int zero = 0; asm volatile("" : "+v"(zero));
        hist[t] = 0;
        gbase[t] = so[t * CHUNKS + j + zero];
        __syncthreads();
        int base = j * EPC + zero;
        int sv[16], dv[16];
        #pragma unroll
        for (int u = 0; u < 16; u++) {
            int i = base + u * 256 + t;         // coalesced
            sv[u] = src[i];
            dv[u] = dst[i];
            atomicAdd(&hist[dv[u] >> 8], 1);
        }
        __syncthreads();
        int hv = hist[t];
        sc[t] = hv;
        __syncthreads();
        for (int o = 1; o < 256; o <<= 1) {
            int u = (t >= o) ? sc[t - o] : 0;
            __syncthreads();
            sc[t] += u;
            __syncthreads();
        }
        int myoff = sc[t] - hv;                 // exclusive local offset
        off[t] = myoff;
        cur[t] = myoff;
        __syncthreads();
        for (int p = myoff, e = myoff + hv; p < e; p++)
            pos2b[p] = (unsigned char)t;        // bucket id per local position
        #pragma unroll
        for (int u = 0; u < 16; u++) {
            int b = dv[u] >> 8;
            int r = atomicAdd(&cur[b], 1);
            sorted[r] = sv[u] | ((dv[u] & 255) << 16);
        }
        __syncthreads();
        #pragma unroll
        for (int u = 0; u < 16; u++) {          // linear LDS read, run-coalesced
            int i = u * 256 + t;                //   global write (runs ~16)
            int b = pos2b[i];
            bpack[gbase[b] + (i - off[b])] = sorted[i];
        }
        __syncthreads();
    }
}

// --- per-bucket: hist -> scan -> row_start+rs_in -> COALESCED csr emit ---
__global__ void bucket_fused(const int* __restrict__ bpack, const int* __restrict__ so,
                             int* __restrict__ row_start, float* __restrict__ rs_in,
                             unsigned short* __restrict__ csr_src) {
    __shared__ int stage[8192];                        // 32 KB
    __shared__ unsigned short sorted[8192];            // 16 KB
    __shared__ int h[256], sc[256], cur[256];
    int b = blockIdx.x;
    int t = threadIdx.x;
    #pragma unroll 1
    for (int rep = 0; rep < BF_REP; rep++) {
        int zero = 0; asm volatile("" : "+v"(zero));
        int beg = so[b * CHUNKS + zero];
        int end = (b == 255) ? N_EDGES : so[(b + 1) * CHUNKS + zero];
        int n = end - beg;
        h[t] = 0;
        __syncthreads();
        for (int i = t; i < n; i += 256) {
            int p = bpack[beg + i];
            if (i < 8192) stage[i] = p;
            atomicAdd(&h[(p >> 16) & 255], 1);
        }
        __syncthreads();
        int d = h[t];
        sc[t] = d;
        __syncthreads();
        for (int off = 1; off < 256; off <<= 1) {
            int v = (t >= off) ? sc[t - off] : 0;
            __syncthreads();
            sc[t] += v;
            __syncthreads();
        }
        int excl = sc[t] - d;                   // local exclusive offset
        int node = b * 256 + t;
        row_start[node] = beg + excl;
        rs_in[node] = rsqrtf(d < 1 ? 1.0f : (float)d);
        if (node == N_NODES - 1) row_start[N_NODES] = N_EDGES;
        cur[t] = excl;
        __syncthreads();
        if (n <= 8192) {                        // always, statistically
            for (int i = t; i < n; i += 256) {
                int p = stage[i];
                int r = atomicAdd(&cur[(p >> 16) & 255], 1);
                sorted[r] = (unsigned short)(p & 0xFFFF);
            }
            __syncthreads();
            for (int i = t; i < n; i += 256)    // fully coalesced 2B stream
                csr_src[beg + i] = sorted[i];
        } else {                                // safety fallback (old path)
            cur[t] = beg + excl;
            __syncthreads();
            for (int i = t; i < n; i += 256) {
                int p = (i < 8192) ? stage[i] : bpack[beg + i];
                int pos = atomicAdd(&cur[(p >> 16) & 255], 1);
                csr_src[pos] = (unsigned short)(p & 0xFFFF);
            }
        }
        __syncthreads();
    }
}

// --- reduce src hists -> rs_out + fp16 prescale; ALL 256 lanes on the reduce ---
__global__ void oh2p_prescale(const unsigned* __restrict__ partial,
                              float* __restrict__ rs_out,
                              const float4* __restrict__ x4, h4* __restrict__ xs) {
    __shared__ int4 psum[256];        // [quarter][word] partial sums
    __shared__ float rsl[256];
    int b = blockIdx.x;
    int t = threadIdx.x;
    #pragma unroll 1
    for (int rep = 0; rep < OH_REP; rep++) {
        int zero = 0; asm volatile("" : "+v"(zero));
        {
            int wl = t & 63;          // word-in-block 0..63
            int q  = t >> 6;          // chunk quarter 0..3
            int w = b * 64 + wl;
            int c0 = 0, c1 = 0, c2 = 0, c3 = 0;
            const unsigned* p = partial + (size_t)(q * (HB / 4)) * OH_WORDS + w + zero;
            #pragma unroll 4
            for (int c = 0; c < HB / 4; c++) {
                unsigned v = p[(size_t)c * OH_WORDS];
                c0 += (int)(v & 255u);
                c1 += (int)((v >> 8) & 255u);
                c2 += (int)((v >> 16) & 255u);
                c3 += (int)(v >> 24);
            }
            psum[t] = make_int4(c0, c1, c2, c3);
        }
        __syncthreads();
        if (t < 64) {
            int4 a = psum[t], b2 = psum[t + 64], c = psum[t + 128], d = psum[t + 192];
            int c0 = a.x + b2.x + c.x + d.x;
            int c1 = a.y + b2.y + c.y + d.y;
            int c2 = a.z + b2.z + c.z + d.z;
            int c3 = a.w + b2.w + c.w + d.w;
            int w = b * 64 + t;
            float4 r = make_float4(rsqrtf(c0 < 1 ? 1.0f : (float)c0),
                                   rsqrtf(c1 < 1 ? 1.0f : (float)c1),
                                   rsqrtf(c2 < 1 ? 1.0f : (float)c2),
                                   rsqrtf(c3 < 1 ? 1.0f : (float)c3));
            ((float4*)rs_out)[w] = r;
            rsl[t * 4 + 0] = r.x; rsl[t * 4 + 1] = r.y;
            rsl[t * 4 + 2] = r.z; rsl[t * 4 + 3] = r.w;
        }
        __syncthreads();
        int rowbase = b * 4096 + zero;    // 256 nodes x 16 float4
        for (int i = t; i < 4096; i += 256) {
            float r = rsl[i >> 4];
            float4 v = x4[rowbase + i];
            h4 o;
            o.a = __float22half2_rn(make_float2(v.x * r, v.y * r));
            o.b = __float22half2_rn(make_float2(v.z * r, v.w * r));
            xs[rowbase + i] = o;
        }
        __syncthreads();
    }
}

// --- fused layer: 8 nodes/wave, 8 lanes/node, 16 edges/batch (R18 exact) ---
template<bool SCALE_OUT>
__global__ void fused_layer(const uint4* __restrict__ xs16, const int* __restrict__ row_start,
                            const unsigned short* __restrict__ csr,
                            const float* __restrict__ rs_out, const float* __restrict__ rs_in,
                            const float* __restrict__ W, const float* __restrict__ b,
                            void* __restrict__ outp) {
    __shared__ float4 Ws4[DIM * 16];   // [row][col/4]
    __shared__ float4 bs4[16];
    {
        const float4* Wg = (const float4*)W;
        for (int i = threadIdx.x; i < DIM * 16; i += blockDim.x) Ws4[i] = Wg[i];
        if (threadIdx.x < 16) bs4[threadIdx.x] = ((const float4*)b)[threadIdx.x];
    }
    __syncthreads();

    int wave_id = threadIdx.x >> 6;
    int lane = threadIdx.x & 63;
    int g = lane >> 3;                 // 8 groups (nodes) per wave
    int l = lane & 7;                  // lane holds dims 8l..8l+7
    int node = blockIdx.x * 32 + wave_id * 8 + g;

    int beg = row_start[node];
    int end = row_start[node + 1];

    float a0 = 0.f, a1 = 0.f, a2 = 0.f, a3 = 0.f,
          a4 = 0.f, a5 = 0.f, a6 = 0.f, a7 = 0.f;
    for (int k = beg; k < end; k += 16) {
        int s[16];
        #pragma unroll
        for (int j = 0; j < 16; j++) {
            int kk = k + j;
            int idx = csr[kk];                         // csr padded by 16 -> safe
            s[j] = (kk < end) ? idx : N_NODES;         // OOB -> zero row (L1-hot)
        }
        uint4 v[16];
        #pragma unroll
        for (int j = 0; j < 16; j++) v[j] = xs16[s[j] * 8 + l];   // 16B/lane
        #pragma unroll
        for (int j = 0; j < 16; j++) {
            float2 f0 = __half22float2(*(const __half2*)&v[j].x);
            float2 f1 = __half22float2(*(const __half2*)&v[j].y);
            float2 f2 = __half22float2(*(const __half2*)&v[j].z);
            float2 f3 = __half22float2(*(const __half2*)&v[j].w);
            a0 += f0.x; a1 += f0.y; a2 += f1.x; a3 += f1.y;
            a4 += f2.x; a5 += f2.y; a6 += f3.x; a7 += f3.y;
        }
    }
    float ri = rs_in[node];
    a0 *= ri; a1 *= ri; a2 *= ri; a3 *= ri;
    a4 *= ri; a5 *= ri; a6 *= ri; a7 *= ri;

    float4 o0 = bs4[2 * l];
    float4 o1 = bs4[2 * l + 1];
    int gbase = g << 3;
    #pragma unroll
    for (int m = 0; m < 8; m++) {
        float q0 = __shfl(a0, gbase + m, 64);
        float q1 = __shfl(a1, gbase + m, 64);
        float q2 = __shfl(a2, gbase + m, 64);
        float q3 = __shfl(a3, gbase + m, 64);
        float q4 = __shfl(a4, gbase + m, 64);
        float q5 = __shfl(a5, gbase + m, 64);
        float q6 = __shfl(a6, gbase + m, 64);
        float q7 = __shfl(a7, gbase + m, 64);
        int rb = (8 * m) * 16 + 2 * l;
        float4 w;
        w = Ws4[rb];            o0.x += q0*w.x; o0.y += q0*w.y; o0.z += q0*w.z; o0.w += q0*w.w;
        w = Ws4[rb + 1];        o1.x += q0*w.x; o1.y += q0*w.y; o1.z += q0*w.z; o1.w += q0*w.w;
        w = Ws4[rb + 16];       o0.x += q1*w.x; o0.y += q1*w.y; o0.z += q1*w.z; o0.w += q1*w.w;
        w = Ws4[rb + 17];       o1.x += q1*w.x; o1.y += q1*w.y; o1.z += q1*w.z; o1.w += q1*w.w;
        w = Ws4[rb + 32];       o0.x += q2*w.x; o0.y += q2*w.y; o0.z += q2*w.z; o0.w += q2*w.w;
        w = Ws4[rb + 33];       o1.x += q2*w.x; o1.y += q2*w.y; o1.z += q2*w.z; o1.w += q2*w.w;
        w = Ws4[rb + 48];       o0.x += q3*w.x; o0.y += q3*w.y; o0.z += q3*w.z; o0.w += q3*w.w;
        w = Ws4[rb + 49];       o1.x += q3*w.x; o1.y += q3*w.y; o1.z += q3*w.z; o1.w += q3*w.w;
        w = Ws4[rb + 64];       o0.x += q4*w.x; o0.y += q4*w.y; o0.z += q4*w.z; o0.w += q4*w.w;
        w = Ws4[rb + 65];       o1.x += q4*w.x; o1.y += q4*w.y; o1.z += q4*w.z; o1.w += q4*w.w;
        w = Ws4[rb + 80];       o0.x += q5*w.x; o0.y += q5*w.y; o0.z += q5*w.z; o0.w += q5*w.w;
        w = Ws4[rb + 81];       o1.x += q5*w.x; o1.y += q5*w.y; o1.z += q5*w.z; o1.w += q5*w.w;
        w = Ws4[rb + 96];       o0.x += q6*w.x; o0.y += q6*w.y; o0.z += q6*w.z; o0.w += q6*w.w;
        w = Ws4[rb + 97];       o1.x += q6*w.x; o1.y += q6*w.y; o1.z += q6*w.z; o1.w += q6*w.w;
        w = Ws4[rb + 112];      o0.x += q7*w.x; o0.y += q7*w.y; o0.z += q7*w.z; o0.w += q7*w.w;
        w = Ws4[rb + 113];      o1.x += q7*w.x; o1.y += q7*w.y; o1.z += q7*w.z; o1.w += q7*w.w;
    }
    if (SCALE_OUT) {
        float ro = rs_out[node];
        o0.x = (o0.x < 0.f ? 0.f : o0.x) * ro;
        o0.y = (o0.y < 0.f ? 0.f : o0.y) * ro;
        o0.z = (o0.z < 0.f ? 0.f : o0.z) * ro;
        o0.w = (o0.w < 0.f ? 0.f : o0.w) * ro;
        o1.x = (o1.x < 0.f ? 0.f : o1.x) * ro;
        o1.y = (o1.y < 0.f ? 0.f : o1.y) * ro;
        o1.z = (o1.z < 0.f ? 0.f : o1.z) * ro;
        o1.w = (o1.w < 0.f ? 0.f : o1.w) * ro;
        uint4 ho;
        *(__half2*)&ho.x = __float22half2_rn(make_float2(o0.x, o0.y));
        *(__half2*)&ho.y = __float22half2_rn(make_float2(o0.z, o0.w));
        *(__half2*)&ho.z = __float22half2_rn(make_float2(o1.x, o1.y));
        *(__half2*)&ho.w = __float22half2_rn(make_float2(o1.z, o1.w));
        ((uint4*)outp)[node * 8 + l] = ho;             // fp16 next-layer table
    } else {
        float4* o4 = (float4*)outp;
        o4[node * 16 + 2 * l]     = o0;                // fp32 final output
        o4[node * 16 + 2 * l + 1] = o1;
    }
}

extern "C" void kernel_launch(void* const* d_in, const int* in_sizes, int n_in,
                              void* d_out, int out_size, void* d_ws, size_t ws_size,
                              hipStream_t stream) {
    const float* x   = (const float*)d_in[0];
    const int*   ei  = (const int*)d_in[1];
    const int*   src = ei;
    const int*   dst = ei + N_EDGES;
    const float* W1 = (const float*)d_in[3];
    const float* b1 = (const float*)d_in[4];
    const float* W2 = (const float*)d_in[5];
    const float* b2 = (const float*)d_in[6];
    const float* W3 = (const float*)d_in[7];
    const float* b3 = (const float*)d_in[8];
    float* out = (float*)d_out;

    // workspace (~28 MB): identical layout to R14/R16/R18/R23.
    char* ws = (char*)d_ws;
    float* rs        = (float*)ws;                                 // [2N]
    float* rs_out    = rs;
    float* rs_in     = rs + N_NODES;
    int*   row_start = (int*)(rs + 2 * N_NODES);                   // [N+256]
    int*   block_h   = row_start + (N_NODES + 256);                // [65536]
    int*   so        = block_h + 256 * CHUNKS;                     // [65536]
    unsigned short* csr_src = (unsigned short*)(so + 256 * CHUNKS);// [E+16]
    h4*    bufA      = (h4*)(csr_src + N_EDGES + 16);              // [(N+1)*16]
    h4*    bufB      = bufA + (size_t)(N_NODES + 1) * 16;          // [(N+1)*16]
    unsigned* partial = (unsigned*)(bufB + (size_t)(N_NODES + 1) * 16); // 8 MB
    int*   bpack     = (int*)bufB;                                 // 4 MB alias
    uint2* zeroA     = (uint2*)(bufA + (size_t)N_NODES * 16);      // row N_NODES
    uint2* zeroB     = (uint2*)(bufB + (size_t)N_NODES * 16);

    const int fb = N_NODES / 32;      // 2048 blocks (8 nodes/wave x 4 waves)

    edge_hist    <<<HB, 256, 0, stream>>>(src, dst, block_h, partial, zeroA, zeroB);
    part_scan    <<<1, 1024, 0, stream>>>(block_h, so);
    part_scatter <<<CHUNKS, 256, 0, stream>>>(src, dst, so, bpack);
    bucket_fused <<<256, 256, 0, stream>>>(bpack, so, row_start, rs_in, csr_src);
    oh2p_prescale<<<256, 256, 0, stream>>>(partial, rs_out, (const float4*)x, bufA);

    // layers: bufA -> bufB(fp16, scaled) -> bufA(fp16, scaled) -> d_out (fp32)
    fused_layer<true ><<<fb, 256, 0, stream>>>((const uint4*)bufA, row_start, csr_src, rs_out, rs_in, W1, b1, (void*)bufB);
    fused_layer<true ><<<fb, 256, 0, stream>>>((const uint4*)bufB, row_start, csr_src, rs_out, rs_in, W2, b2, (void*)bufA);
    fused_layer<false><<<fb, 256, 0, stream>>>((const uint4*)bufA, row_start, csr_src, rs_out, rs_in, W3, b3, (void*)out);
}

// Round 9
// 358.792 us; speedup vs baseline: 2.0204x; 2.0204x over previous
//
#include <hip/hip_runtime.h>
#include <hip/hip_fp16.h>
#include <hip/hip_cooperative_groups.h>

namespace cg = cooperative_groups;

// GraphEncoder: 3x GraphConv(norm='both'), DIM=64, fixed graph.
// R25: R24 diagnostic showed the pipeline is DISPATCH-BOUND: preproc kernels
// execute in ~40us total (17.3us of it the single-block part_scan), layers
// ~94us, and ~100us is launch gaps/overhead across 8 dispatches. Fix: fuse
// all 5 preproc kernels into ONE cooperative kernel (256 blocks, grid.sync
// between phases), with part_scan replaced by a 2-level hierarchical scan
// (exact same integer results). Dispatches 8 -> 4. Layers exact R18.
// All arithmetic bit-identical -> absmax unchanged.

#define N_NODES 65536
#define N_EDGES 1048576
#define DIM 64

#define CHUNKS 256
#define EPC (N_EDGES / CHUNKS)        // 4096 edges per chunk
#define HB 128                        // hist phase blocks (2 chunks each)
#define OH_WORDS 16384                // 65536 nodes packed 4-per-word (64KB)

struct alignas(8) h4 { __half2 a, b; };   // 4 halves = 8 B

// ---- fused preprocessing: hist -> scan -> scatter -> bucket -> prescale ----
__global__ void __launch_bounds__(256) preproc_fused(
    const int* __restrict__ src, const int* __restrict__ dst,
    int* __restrict__ block_h, unsigned* __restrict__ partial,
    int* __restrict__ so, int* __restrict__ rowtot,
    int* __restrict__ bpack, int* __restrict__ row_start,
    float* __restrict__ rs_in, float* __restrict__ rs_out,
    const float4* __restrict__ x4, h4* __restrict__ xs,
    unsigned short* __restrict__ csr_src,
    uint2* __restrict__ zeroA, uint2* __restrict__ zeroB)
{
    cg::grid_group grid = cg::this_grid();
    __shared__ __align__(16) char sm[67584];   // 66 KB, reused per phase
    const int t = threadIdx.x;
    const int b = blockIdx.x;

    // ---------- Phase A: edge hist (blocks 0..127, 2 chunks each) ----------
    if (b < HB) {
        unsigned* h = (unsigned*)sm;                  // 64 KB packed src hist
        int* bh = (int*)(sm + OH_WORDS * 4);          // 2 KB [2][256]
        for (int i = t; i < OH_WORDS; i += 256) h[i] = 0;
        bh[t] = 0; bh[256 + t] = 0;
        __syncthreads();
        if (b == 0) {                 // zero row (row N_NODES, 128 B each table)
            if (t < 16) zeroA[t] = make_uint2(0u, 0u);
            else if (t < 32) zeroB[t - 16] = make_uint2(0u, 0u);
        }
        int base = b * (2 * EPC);
        for (int i = t; i < 2 * EPC; i += 256) {
            int s = src[base + i];
            int d = dst[base + i];
            atomicAdd(&h[s >> 2], 1u << ((s & 3) * 8));
            atomicAdd(&bh[(i >> 12) * 256 + (d >> 8)], 1);
        }
        __syncthreads();
        unsigned* dp = partial + (size_t)b * OH_WORDS;
        for (int i = t; i < OH_WORDS; i += 256) dp[i] = h[i];
        block_h[t * CHUNKS + 2 * b]     = bh[t];
        block_h[t * CHUNKS + 2 * b + 1] = bh[256 + t];
    }
    grid.sync();   // block_h + partial visible

    // ---------- Phase B1: per-bucket row scan (block b = bucket b) ----------
    int* lscan = (int*)sm;                            // [256] lives until B2
    {
        int* tmp = (int*)(sm + 1024);                 // [256]
        int v = block_h[b * CHUNKS + t];
        tmp[t] = v;
        __syncthreads();
        for (int off = 1; off < 256; off <<= 1) {
            int u = (t >= off) ? tmp[t - off] : 0;
            __syncthreads();
            tmp[t] += u;
            __syncthreads();
        }
        lscan[t] = tmp[t] - v;                        // exclusive within row
        if (t == 255) rowtot[b] = tmp[255];
    }
    // ---------- Phase E (independent): partial reduce -> rs_out + prescale ----
    {
        int4* psum = (int4*)(sm + 2048);              // 4 KB
        float* rsl = (float*)(sm + 2048 + 4096);      // 1 KB
        int wl = t & 63;
        int q  = t >> 6;
        int w = b * 64 + wl;
        int c0 = 0, c1 = 0, c2 = 0, c3 = 0;
        const unsigned* p = partial + (size_t)(q * (HB / 4)) * OH_WORDS + w;
        #pragma unroll 4
        for (int c = 0; c < HB / 4; c++) {
            unsigned v = p[(size_t)c * OH_WORDS];
            c0 += (int)(v & 255u);
            c1 += (int)((v >> 8) & 255u);
            c2 += (int)((v >> 16) & 255u);
            c3 += (int)(v >> 24);
        }
        psum[t] = make_int4(c0, c1, c2, c3);
        __syncthreads();
        if (t < 64) {
            int4 a = psum[t], b2 = psum[t + 64], c = psum[t + 128], d = psum[t + 192];
            int d0 = a.x + b2.x + c.x + d.x;
            int d1 = a.y + b2.y + c.y + d.y;
            int d2 = a.z + b2.z + c.z + d.z;
            int d3 = a.w + b2.w + c.w + d.w;
            int w2 = b * 64 + t;
            float4 r = make_float4(rsqrtf(d0 < 1 ? 1.0f : (float)d0),
                                   rsqrtf(d1 < 1 ? 1.0f : (float)d1),
                                   rsqrtf(d2 < 1 ? 1.0f : (float)d2),
                                   rsqrtf(d3 < 1 ? 1.0f : (float)d3));
            ((float4*)rs_out)[w2] = r;
            rsl[t * 4 + 0] = r.x; rsl[t * 4 + 1] = r.y;
            rsl[t * 4 + 2] = r.z; rsl[t * 4 + 3] = r.w;
        }
        __syncthreads();
        int rowbase = b * 4096;           // 256 nodes x 16 float4
        for (int i = t; i < 4096; i += 256) {
            float r = rsl[i >> 4];
            float4 v = x4[rowbase + i];
            h4 o;
            o.a = __float22half2_rn(make_float2(v.x * r, v.y * r));
            o.b = __float22half2_rn(make_float2(v.z * r, v.w * r));
            xs[rowbase + i] = o;
        }
    }
    grid.sync();   // rowtot visible

    // ---------- Phase B2: bucket offsets, write so ----------
    {
        int* tot  = (int*)(sm + 2048);                // [256]
        int* orig = (int*)(sm + 3072);                // [256]
        int v = rowtot[t];
        tot[t] = v; orig[t] = v;
        __syncthreads();
        for (int off = 1; off < 256; off <<= 1) {
            int u = (t >= off) ? tot[t - off] : 0;
            __syncthreads();
            tot[t] += u;
            __syncthreads();
        }
        int rowoff = tot[b] - orig[b];                // exclusive prefix of row b
        so[b * CHUNKS + t] = rowoff + lscan[t];
    }
    grid.sync();   // so complete

    // ---------- Phase C: coalesced counting-sort scatter (chunk b) ----------
    {
        int* hist = (int*)sm;                         // [256]
        int* sc   = (int*)(sm + 1024);                // [256]
        int* offv = (int*)(sm + 2048);                // [256]
        int* cur  = (int*)(sm + 3072);                // [256]
        int* gb   = (int*)(sm + 4096);                // [256]
        int* sorted = (int*)(sm + 5120);              // 16 KB
        unsigned char* pos2b = (unsigned char*)(sm + 5120 + 16384); // 4 KB
        hist[t] = 0;
        gb[t] = so[t * CHUNKS + b];
        __syncthreads();
        int base = b * EPC;
        int sv[16], dv[16];
        #pragma unroll
        for (int u = 0; u < 16; u++) {
            int i = base + u * 256 + t;               // coalesced
            sv[u] = src[i];
            dv[u] = dst[i];
            atomicAdd(&hist[dv[u] >> 8], 1);
        }
        __syncthreads();
        int hv = hist[t];
        sc[t] = hv;
        __syncthreads();
        for (int o = 1; o < 256; o <<= 1) {
            int u = (t >= o) ? sc[t - o] : 0;
            __syncthreads();
            sc[t] += u;
            __syncthreads();
        }
        int myoff = sc[t] - hv;
        offv[t] = myoff;
        cur[t] = myoff;
        __syncthreads();
        for (int p = myoff, e = myoff + hv; p < e; p++)
            pos2b[p] = (unsigned char)t;
        #pragma unroll
        for (int u = 0; u < 16; u++) {
            int bb = dv[u] >> 8;
            int r = atomicAdd(&cur[bb], 1);
            sorted[r] = sv[u] | ((dv[u] & 255) << 16);
        }
        __syncthreads();
        #pragma unroll
        for (int u = 0; u < 16; u++) {                // run-coalesced writeout
            int i = u * 256 + t;
            int bb = pos2b[i];
            bpack[gb[bb] + (i - offv[bb])] = sorted[i];
        }
    }
    grid.sync();   // bpack complete

    // ---------- Phase D: per-bucket row_start/rs_in + coalesced csr ----------
    {
        int* stage = (int*)sm;                                // 32 KB
        unsigned short* sorted = (unsigned short*)(sm + 32768); // 16 KB
        int* h   = (int*)(sm + 32768 + 16384);                // [256]
        int* sc  = (int*)(sm + 32768 + 16384 + 1024);         // [256]
        int* cur = (int*)(sm + 32768 + 16384 + 2048);         // [256]
        int beg = so[b * CHUNKS];
        int end = (b == 255) ? N_EDGES : so[(b + 1) * CHUNKS];
        int n = end - beg;
        h[t] = 0;
        __syncthreads();
        for (int i = t; i < n; i += 256) {
            int p = bpack[beg + i];
            if (i < 8192) stage[i] = p;
            atomicAdd(&h[(p >> 16) & 255], 1);
        }
        __syncthreads();
        int d = h[t];
        sc[t] = d;
        __syncthreads();
        for (int off = 1; off < 256; off <<= 1) {
            int v = (t >= off) ? sc[t - off] : 0;
            __syncthreads();
            sc[t] += v;
            __syncthreads();
        }
        int excl = sc[t] - d;
        int node = b * 256 + t;
        row_start[node] = beg + excl;
        rs_in[node] = rsqrtf(d < 1 ? 1.0f : (float)d);
        if (node == N_NODES - 1) row_start[N_NODES] = N_EDGES;
        cur[t] = excl;
        __syncthreads();
        if (n <= 8192) {                              // always, statistically
            for (int i = t; i < n; i += 256) {
                int p = stage[i];
                int r = atomicAdd(&cur[(p >> 16) & 255], 1);
                sorted[r] = (unsigned short)(p & 0xFFFF);
            }
            __syncthreads();
            for (int i = t; i < n; i += 256)          // coalesced 2B stream
                csr_src[beg + i] = sorted[i];
        } else {                                      // safety fallback
            cur[t] = beg + excl;
            __syncthreads();
            for (int i = t; i < n; i += 256) {
                int p = (i < 8192) ? stage[i] : bpack[beg + i];
                int pos = atomicAdd(&cur[(p >> 16) & 255], 1);
                csr_src[pos] = (unsigned short)(p & 0xFFFF);
            }
        }
    }
}

// --- fused layer: 8 nodes/wave, 8 lanes/node, 16 edges/batch (R18 exact) ---
template<bool SCALE_OUT>
__global__ void fused_layer(const uint4* __restrict__ xs16, const int* __restrict__ row_start,
                            const unsigned short* __restrict__ csr,
                            const float* __restrict__ rs_out, const float* __restrict__ rs_in,
                            const float* __restrict__ W, const float* __restrict__ b,
                            void* __restrict__ outp) {
    __shared__ float4 Ws4[DIM * 16];   // [row][col/4]
    __shared__ float4 bs4[16];
    {
        const float4* Wg = (const float4*)W;
        for (int i = threadIdx.x; i < DIM * 16; i += blockDim.x) Ws4[i] = Wg[i];
        if (threadIdx.x < 16) bs4[threadIdx.x] = ((const float4*)b)[threadIdx.x];
    }
    __syncthreads();

    int wave_id = threadIdx.x >> 6;
    int lane = threadIdx.x & 63;
    int g = lane >> 3;                 // 8 groups (nodes) per wave
    int l = lane & 7;                  // lane holds dims 8l..8l+7
    int node = blockIdx.x * 32 + wave_id * 8 + g;

    int beg = row_start[node];
    int end = row_start[node + 1];

    float a0 = 0.f, a1 = 0.f, a2 = 0.f, a3 = 0.f,
          a4 = 0.f, a5 = 0.f, a6 = 0.f, a7 = 0.f;
    for (int k = beg; k < end; k += 16) {
        int s[16];
        #pragma unroll
        for (int j = 0; j < 16; j++) {
            int kk = k + j;
            int idx = csr[kk];                         // csr padded by 16 -> safe
            s[j] = (kk < end) ? idx : N_NODES;         // OOB -> zero row (L1-hot)
        }
        uint4 v[16];
        #pragma unroll
        for (int j = 0; j < 16; j++) v[j] = xs16[s[j] * 8 + l];   // 16B/lane
        #pragma unroll
        for (int j = 0; j < 16; j++) {
            float2 f0 = __half22float2(*(const __half2*)&v[j].x);
            float2 f1 = __half22float2(*(const __half2*)&v[j].y);
            float2 f2 = __half22float2(*(const __half2*)&v[j].z);
            float2 f3 = __half22float2(*(const __half2*)&v[j].w);
            a0 += f0.x; a1 += f0.y; a2 += f1.x; a3 += f1.y;
            a4 += f2.x; a5 += f2.y; a6 += f3.x; a7 += f3.y;
        }
    }
    float ri = rs_in[node];
    a0 *= ri; a1 *= ri; a2 *= ri; a3 *= ri;
    a4 *= ri; a5 *= ri; a6 *= ri; a7 *= ri;

    float4 o0 = bs4[2 * l];
    float4 o1 = bs4[2 * l + 1];
    int gbase = g << 3;
    #pragma unroll
    for (int m = 0; m < 8; m++) {
        float q0 = __shfl(a0, gbase + m, 64);
        float q1 = __shfl(a1, gbase + m, 64);
        float q2 = __shfl(a2, gbase + m, 64);
        float q3 = __shfl(a3, gbase + m, 64);
        float q4 = __shfl(a4, gbase + m, 64);
        float q5 = __shfl(a5, gbase + m, 64);
        float q6 = __shfl(a6, gbase + m, 64);
        float q7 = __shfl(a7, gbase + m, 64);
        int rb = (8 * m) * 16 + 2 * l;
        float4 w;
        w = Ws4[rb];            o0.x += q0*w.x; o0.y += q0*w.y; o0.z += q0*w.z; o0.w += q0*w.w;
        w = Ws4[rb + 1];        o1.x += q0*w.x; o1.y += q0*w.y; o1.z += q0*w.z; o1.w += q0*w.w;
        w = Ws4[rb + 16];       o0.x += q1*w.x; o0.y += q1*w.y; o0.z += q1*w.z; o0.w += q1*w.w;
        w = Ws4[rb + 17];       o1.x += q1*w.x; o1.y += q1*w.y; o1.z += q1*w.z; o1.w += q1*w.w;
        w = Ws4[rb + 32];       o0.x += q2*w.x; o0.y += q2*w.y; o0.z += q2*w.z; o0.w += q2*w.w;
        w = Ws4[rb + 33];       o1.x += q2*w.x; o1.y += q2*w.y; o1.z += q2*w.z; o1.w += q2*w.w;
        w = Ws4[rb + 48];       o0.x += q3*w.x; o0.y += q3*w.y; o0.z += q3*w.z; o0.w += q3*w.w;
        w = Ws4[rb + 49];       o1.x += q3*w.x; o1.y += q3*w.y; o1.z += q3*w.z; o1.w += q3*w.w;
        w = Ws4[rb + 64];       o0.x += q4*w.x; o0.y += q4*w.y; o0.z += q4*w.z; o0.w += q4*w.w;
        w = Ws4[rb + 65];       o1.x += q4*w.x; o1.y += q4*w.y; o1.z += q4*w.z; o1.w += q4*w.w;
        w = Ws4[rb + 80];       o0.x += q5*w.x; o0.y += q5*w.y; o0.z += q5*w.z; o0.w += q5*w.w;
        w = Ws4[rb + 81];       o1.x += q5*w.x; o1.y += q5*w.y; o1.z += q5*w.z; o1.w += q5*w.w;
        w = Ws4[rb + 96];       o0.x += q6*w.x; o0.y += q6*w.y; o0.z += q6*w.z; o0.w += q6*w.w;
        w = Ws4[rb + 97];       o1.x += q6*w.x; o1.y += q6*w.y; o1.z += q6*w.z; o1.w += q6*w.w;
        w = Ws4[rb + 112];      o0.x += q7*w.x; o0.y += q7*w.y; o0.z += q7*w.z; o0.w += q7*w.w;
        w = Ws4[rb + 113];      o1.x += q7*w.x; o1.y += q7*w.y; o1.z += q7*w.z; o1.w += q7*w.w;
    }
    if (SCALE_OUT) {
        float ro = rs_out[node];
        o0.x = (o0.x < 0.f ? 0.f : o0.x) * ro;
        o0.y = (o0.y < 0.f ? 0.f : o0.y) * ro;
        o0.z = (o0.z < 0.f ? 0.f : o0.z) * ro;
        o0.w = (o0.w < 0.f ? 0.f : o0.w) * ro;
        o1.x = (o1.x < 0.f ? 0.f : o1.x) * ro;
        o1.y = (o1.y < 0.f ? 0.f : o1.y) * ro;
        o1.z = (o1.z < 0.f ? 0.f : o1.z) * ro;
        o1.w = (o1.w < 0.f ? 0.f : o1.w) * ro;
        uint4 ho;
        *(__half2*)&ho.x = __float22half2_rn(make_float2(o0.x, o0.y));
        *(__half2*)&ho.y = __float22half2_rn(make_float2(o0.z, o0.w));
        *(__half2*)&ho.z = __float22half2_rn(make_float2(o1.x, o1.y));
        *(__half2*)&ho.w = __float22half2_rn(make_float2(o1.z, o1.w));
        ((uint4*)outp)[node * 8 + l] = ho;             // fp16 next-layer table
    } else {
        float4* o4 = (float4*)outp;
        o4[node * 16 + 2 * l]     = o0;                // fp32 final output
        o4[node * 16 + 2 * l + 1] = o1;
    }
}

extern "C" void kernel_launch(void* const* d_in, const int* in_sizes, int n_in,
                              void* d_out, int out_size, void* d_ws, size_t ws_size,
                              hipStream_t stream) {
    const float* x   = (const float*)d_in[0];
    const int*   ei  = (const int*)d_in[1];
    const int*   src = ei;
    const int*   dst = ei + N_EDGES;
    const float* W1 = (const float*)d_in[3];
    const float* b1 = (const float*)d_in[4];
    const float* W2 = (const float*)d_in[5];
    const float* b2 = (const float*)d_in[6];
    const float* W3 = (const float*)d_in[7];
    const float* b3 = (const float*)d_in[8];
    float* out = (float*)d_out;

    // workspace (~28.3 MB): R23 layout + rowtot (1 KB) after partial.
    char* ws = (char*)d_ws;
    float* rs        = (float*)ws;                                 // [2N]
    float* rs_out    = rs;
    float* rs_in     = rs + N_NODES;
    int*   row_start = (int*)(rs + 2 * N_NODES);                   // [N+256]
    int*   block_h   = row_start + (N_NODES + 256);                // [65536]
    int*   so        = block_h + 256 * CHUNKS;                     // [65536]
    unsigned short* csr_src = (unsigned short*)(so + 256 * CHUNKS);// [E+16]
    h4*    bufA      = (h4*)(csr_src + N_EDGES + 16);              // [(N+1)*16]
    h4*    bufB      = bufA + (size_t)(N_NODES + 1) * 16;          // [(N+1)*16]
    unsigned* partial = (unsigned*)(bufB + (size_t)(N_NODES + 1) * 16); // 8 MB
    int*   rowtot    = (int*)(partial + (size_t)HB * OH_WORDS);    // [256]
    int*   bpack     = (int*)bufB;                                 // 4 MB alias
    uint2* zeroA     = (uint2*)(bufA + (size_t)N_NODES * 16);      // row N_NODES
    uint2* zeroB     = (uint2*)(bufB + (size_t)N_NODES * 16);

    const int fb = N_NODES / 32;      // 2048 blocks (8 nodes/wave x 4 waves)

    {
        const float4* x4p = (const float4*)x;
        h4* xsA = bufA;
        void* args[] = { (void*)&src, (void*)&dst, (void*)&block_h, (void*)&partial,
                         (void*)&so, (void*)&rowtot, (void*)&bpack, (void*)&row_start,
                         (void*)&rs_in, (void*)&rs_out, (void*)&x4p, (void*)&xsA,
                         (void*)&csr_src, (void*)&zeroA, (void*)&zeroB };
        hipLaunchCooperativeKernel((void*)preproc_fused, dim3(256), dim3(256),
                                   args, 0, stream);
    }

    // layers: bufA -> bufB(fp16, scaled) -> bufA(fp16, scaled) -> d_out (fp32)
    fused_layer<true ><<<fb, 256, 0, stream>>>((const uint4*)bufA, row_start, csr_src, rs_out, rs_in, W1, b1, (void*)bufB);
    fused_layer<true ><<<fb, 256, 0, stream>>>((const uint4*)bufB, row_start, csr_src, rs_out, rs_in, W2, b2, (void*)bufA);
    fused_layer<false><<<fb, 256, 0, stream>>>((const uint4*)bufA, row_start, csr_src, rs_out, rs_in, W3, b3, (void*)out);
}

// Round 10
// 221.750 us; speedup vs baseline: 3.2691x; 1.6180x over previous
//
#include <hip/hip_runtime.h>
#include <hip/hip_fp16.h>

// GraphEncoder: 3x GraphConv(norm='both'), DIM=64, fixed graph.
// R26: revert R25's cooperative fusion (158us fused vs 40us split: grid.sync
// + 1-block/CU residency cost ~120us). Back to R23 (best, 236.6us) + ONE
// surgical change from the R24 measurement: part_scan (17.3us, SINGLE-block
// serial scan) is eliminated.
//  - scan_oh2p (256 blocks): block b scans block_h row b (lscan+rowtot)
//    AND runs the old oh2p_prescale body (independent work, same shape)
//    -> two kernels merged, dispatches 8 -> 7.
//  - part_scatter/bucket_fused prepend a 256-wide rowtot scan (~0.5us) to
//    rebuild so[b][c] = rowoff[b]+lscan[b][c] exactly.
// Integer scan arithmetic identical -> bit-identical outputs.

#define N_NODES 65536
#define N_EDGES 1048576
#define DIM 64

#define CHUNKS 256
#define EPC (N_EDGES / CHUNKS)        // 4096 edges per scatter chunk
#define HB 128                        // edge_hist blocks (2 chunks each)
#define OH_WORDS 16384                // 65536 nodes packed 4-per-word (64KB)

struct alignas(8) h4 { __half2 a, b; };   // 4 halves = 8 B

// --- one pass over edges: dst partition hist + packed src hist + zero rows ---
__global__ void edge_hist(const int* __restrict__ src, const int* __restrict__ dst,
                          int* __restrict__ block_hist, unsigned* __restrict__ partial,
                          uint2* __restrict__ zeroA, uint2* __restrict__ zeroB) {
    __shared__ unsigned h[OH_WORDS];  // 64 KB: src histogram, 8-bit x4 packed
    __shared__ int bh[2][256];
    int t = threadIdx.x;
    int j = blockIdx.x;               // 0..127
    for (int i = t; i < OH_WORDS; i += 256) h[i] = 0;
    bh[0][t] = 0; bh[1][t] = 0;
    __syncthreads();
    if (j == 0) {                     // zero row (row N_NODES, 128 B each table)
        if (t < 16) zeroA[t] = make_uint2(0u, 0u);
        else if (t < 32) zeroB[t - 16] = make_uint2(0u, 0u);
    }
    int base = j * (2 * EPC);
    for (int i = t; i < 2 * EPC; i += 256) {
        int s = src[base + i];
        int d = dst[base + i];
        atomicAdd(&h[s >> 2], 1u << ((s & 3) * 8));
        atomicAdd(&bh[i >> 12][d >> 8], 1);
    }
    __syncthreads();
    unsigned* dp = partial + (size_t)j * OH_WORDS;
    for (int i = t; i < OH_WORDS; i += 256) dp[i] = h[i];
    block_hist[t * CHUNKS + 2 * j]     = bh[0][t];
    block_hist[t * CHUNKS + 2 * j + 1] = bh[1][t];
}

// --- merged: per-bucket row scan (replaces part_scan) + oh2p_prescale ---
__global__ void scan_oh2p(const int* __restrict__ block_h, int* __restrict__ lscan,
                          int* __restrict__ rowtot,
                          const unsigned* __restrict__ partial,
                          float* __restrict__ rs_out,
                          const float4* __restrict__ x4, h4* __restrict__ xs) {
    __shared__ int tmp[256];
    __shared__ int4 psum[256];
    __shared__ float rsl[256];
    int b = blockIdx.x;
    int t = threadIdx.x;
    // ---- scan row b of block_h (bucket-major [bucket][chunk]) ----
    {
        int v = block_h[b * CHUNKS + t];
        tmp[t] = v;
        __syncthreads();
        for (int off = 1; off < 256; off <<= 1) {
            int u = (t >= off) ? tmp[t - off] : 0;
            __syncthreads();
            tmp[t] += u;
            __syncthreads();
        }
        lscan[b * CHUNKS + t] = tmp[t] - v;       // exclusive within row
        if (t == 255) rowtot[b] = tmp[255];
    }
    // ---- old oh2p_prescale body (independent of the scan) ----
    {
        int wl = t & 63;              // word-in-block 0..63
        int q  = t >> 6;              // chunk quarter 0..3
        int w = b * 64 + wl;
        int c0 = 0, c1 = 0, c2 = 0, c3 = 0;
        const unsigned* p = partial + (size_t)(q * (HB / 4)) * OH_WORDS + w;
        #pragma unroll 4
        for (int c = 0; c < HB / 4; c++) {
            unsigned v = p[(size_t)c * OH_WORDS];
            c0 += (int)(v & 255u);
            c1 += (int)((v >> 8) & 255u);
            c2 += (int)((v >> 16) & 255u);
            c3 += (int)(v >> 24);
        }
        psum[t] = make_int4(c0, c1, c2, c3);
    }
    __syncthreads();
    if (t < 64) {
        int4 a = psum[t], b2 = psum[t + 64], c = psum[t + 128], d = psum[t + 192];
        int c0 = a.x + b2.x + c.x + d.x;
        int c1 = a.y + b2.y + c.y + d.y;
        int c2 = a.z + b2.z + c.z + d.z;
        int c3 = a.w + b2.w + c.w + d.w;
        int w = b * 64 + t;
        float4 r = make_float4(rsqrtf(c0 < 1 ? 1.0f : (float)c0),
                               rsqrtf(c1 < 1 ? 1.0f : (float)c1),
                               rsqrtf(c2 < 1 ? 1.0f : (float)c2),
                               rsqrtf(c3 < 1 ? 1.0f : (float)c3));
        ((float4*)rs_out)[w] = r;
        rsl[t * 4 + 0] = r.x; rsl[t * 4 + 1] = r.y;
        rsl[t * 4 + 2] = r.z; rsl[t * 4 + 3] = r.w;
    }
    __syncthreads();
    int rowbase = b * 4096;           // 256 nodes x 16 float4
    for (int i = t; i < 4096; i += 256) {
        float r = rsl[i >> 4];
        float4 v = x4[rowbase + i];
        h4 o;
        o.a = __float22half2_rn(make_float2(v.x * r, v.y * r));
        o.b = __float22half2_rn(make_float2(v.z * r, v.w * r));
        xs[rowbase + i] = o;
    }
}

// --- scatter into bucket order, COALESCED counting sort (R23-proven) ---
__global__ void part_scatter(const int* __restrict__ src, const int* __restrict__ dst,
                             const int* __restrict__ lscan, const int* __restrict__ rowtot,
                             int* __restrict__ bpack) {
    __shared__ int hist[256], sc[256], off[256], cur[256], gbase[256];
    __shared__ int sorted[EPC];                 // 16 KB, bucket-ordered edges
    __shared__ unsigned char pos2b[EPC];        // 4 KB, position -> bucket
    int t = threadIdx.x;
    int j = blockIdx.x;
    // rebuild so[t][j] = rowoff[t] + lscan[t][j]  (sc as scratch)
    {
        int rv = rowtot[t];
        sc[t] = rv;
        __syncthreads();
        for (int o = 1; o < 256; o <<= 1) {
            int u = (t >= o) ? sc[t - o] : 0;
            __syncthreads();
            sc[t] += u;
            __syncthreads();
        }
        gbase[t] = (sc[t] - rv) + lscan[t * CHUNKS + j];
    }
    hist[t] = 0;
    __syncthreads();
    int base = j * EPC;
    int sv[16], dv[16];
    #pragma unroll
    for (int u = 0; u < 16; u++) {
        int i = base + u * 256 + t;             // coalesced
        sv[u] = src[i];
        dv[u] = dst[i];
        atomicAdd(&hist[dv[u] >> 8], 1);
    }
    __syncthreads();
    int hv = hist[t];
    sc[t] = hv;
    __syncthreads();
    for (int o = 1; o < 256; o <<= 1) {
        int u = (t >= o) ? sc[t - o] : 0;
        __syncthreads();
        sc[t] += u;
        __syncthreads();
    }
    int myoff = sc[t] - hv;                     // exclusive local offset
    off[t] = myoff;
    cur[t] = myoff;
    __syncthreads();
    for (int p = myoff, e = myoff + hv; p < e; p++)
        pos2b[p] = (unsigned char)t;            // bucket id per local position
    #pragma unroll
    for (int u = 0; u < 16; u++) {
        int b = dv[u] >> 8;
        int r = atomicAdd(&cur[b], 1);
        sorted[r] = sv[u] | ((dv[u] & 255) << 16);
    }
    __syncthreads();
    #pragma unroll
    for (int u = 0; u < 16; u++) {              // linear LDS read, run-coalesced
        int i = u * 256 + t;                    //   global write (runs ~16)
        int b = pos2b[i];
        bpack[gbase[b] + (i - off[b])] = sorted[i];
    }
}

// --- per-bucket: hist -> scan -> row_start+rs_in -> COALESCED csr emit ---
__global__ void bucket_fused(const int* __restrict__ bpack, const int* __restrict__ rowtot,
                             int* __restrict__ row_start, float* __restrict__ rs_in,
                             unsigned short* __restrict__ csr_src) {
    __shared__ int stage[8192];                        // 32 KB
    __shared__ unsigned short sorted[8192];            // 16 KB
    __shared__ int h[256], sc[256], cur[256], ro[256];
    int b = blockIdx.x;
    int t = threadIdx.x;
    // rebuild rowoff (exclusive scan of rowtot)
    {
        int rv = rowtot[t];
        sc[t] = rv;
        __syncthreads();
        for (int o = 1; o < 256; o <<= 1) {
            int u = (t >= o) ? sc[t - o] : 0;
            __syncthreads();
            sc[t] += u;
            __syncthreads();
        }
        ro[t] = sc[t] - rv;
    }
    __syncthreads();
    int beg = ro[b];
    int end = (b == 255) ? N_EDGES : ro[b + 1];
    int n = end - beg;
    h[t] = 0;
    __syncthreads();
    for (int i = t; i < n; i += 256) {
        int p = bpack[beg + i];
        if (i < 8192) stage[i] = p;
        atomicAdd(&h[(p >> 16) & 255], 1);
    }
    __syncthreads();
    int d = h[t];
    sc[t] = d;
    __syncthreads();
    for (int off = 1; off < 256; off <<= 1) {
        int v = (t >= off) ? sc[t - off] : 0;
        __syncthreads();
        sc[t] += v;
        __syncthreads();
    }
    int excl = sc[t] - d;                       // local exclusive offset
    int node = b * 256 + t;
    row_start[node] = beg + excl;
    rs_in[node] = rsqrtf(d < 1 ? 1.0f : (float)d);
    if (node == N_NODES - 1) row_start[N_NODES] = N_EDGES;
    cur[t] = excl;
    __syncthreads();
    if (n <= 8192) {                            // always, statistically
        for (int i = t; i < n; i += 256) {
            int p = stage[i];
            int r = atomicAdd(&cur[(p >> 16) & 255], 1);
            sorted[r] = (unsigned short)(p & 0xFFFF);
        }
        __syncthreads();
        for (int i = t; i < n; i += 256)        // fully coalesced 2B stream
            csr_src[beg + i] = sorted[i];
    } else {                                    // safety fallback (old path)
        cur[t] = beg + excl;
        __syncthreads();
        for (int i = t; i < n; i += 256) {
            int p = (i < 8192) ? stage[i] : bpack[beg + i];
            int pos = atomicAdd(&cur[(p >> 16) & 255], 1);
            csr_src[pos] = (unsigned short)(p & 0xFFFF);
        }
    }
}

// --- fused layer: 8 nodes/wave, 8 lanes/node, 16 edges/batch (R18 exact) ---
template<bool SCALE_OUT>
__global__ void fused_layer(const uint4* __restrict__ xs16, const int* __restrict__ row_start,
                            const unsigned short* __restrict__ csr,
                            const float* __restrict__ rs_out, const float* __restrict__ rs_in,
                            const float* __restrict__ W, const float* __restrict__ b,
                            void* __restrict__ outp) {
    __shared__ float4 Ws4[DIM * 16];   // [row][col/4]
    __shared__ float4 bs4[16];
    {
        const float4* Wg = (const float4*)W;
        for (int i = threadIdx.x; i < DIM * 16; i += blockDim.x) Ws4[i] = Wg[i];
        if (threadIdx.x < 16) bs4[threadIdx.x] = ((const float4*)b)[threadIdx.x];
    }
    __syncthreads();

    int wave_id = threadIdx.x >> 6;
    int lane = threadIdx.x & 63;
    int g = lane >> 3;                 // 8 groups (nodes) per wave
    int l = lane & 7;                  // lane holds dims 8l..8l+7
    int node = blockIdx.x * 32 + wave_id * 8 + g;

    int beg = row_start[node];
    int end = row_start[node + 1];

    float a0 = 0.f, a1 = 0.f, a2 = 0.f, a3 = 0.f,
          a4 = 0.f, a5 = 0.f, a6 = 0.f, a7 = 0.f;
    for (int k = beg; k < end; k += 16) {
        int s[16];
        #pragma unroll
        for (int j = 0; j < 16; j++) {
            int kk = k + j;
            int idx = csr[kk];                         // csr padded by 16 -> safe
            s[j] = (kk < end) ? idx : N_NODES;         // OOB -> zero row (L1-hot)
        }
        uint4 v[16];
        #pragma unroll
        for (int j = 0; j < 16; j++) v[j] = xs16[s[j] * 8 + l];   // 16B/lane
        #pragma unroll
        for (int j = 0; j < 16; j++) {
            float2 f0 = __half22float2(*(const __half2*)&v[j].x);
            float2 f1 = __half22float2(*(const __half2*)&v[j].y);
            float2 f2 = __half22float2(*(const __half2*)&v[j].z);
            float2 f3 = __half22float2(*(const __half2*)&v[j].w);
            a0 += f0.x; a1 += f0.y; a2 += f1.x; a3 += f1.y;
            a4 += f2.x; a5 += f2.y; a6 += f3.x; a7 += f3.y;
        }
    }
    float ri = rs_in[node];
    a0 *= ri; a1 *= ri; a2 *= ri; a3 *= ri;
    a4 *= ri; a5 *= ri; a6 *= ri; a7 *= ri;

    float4 o0 = bs4[2 * l];
    float4 o1 = bs4[2 * l + 1];
    int gbase = g << 3;
    #pragma unroll
    for (int m = 0; m < 8; m++) {
        float q0 = __shfl(a0, gbase + m, 64);
        float q1 = __shfl(a1, gbase + m, 64);
        float q2 = __shfl(a2, gbase + m, 64);
        float q3 = __shfl(a3, gbase + m, 64);
        float q4 = __shfl(a4, gbase + m, 64);
        float q5 = __shfl(a5, gbase + m, 64);
        float q6 = __shfl(a6, gbase + m, 64);
        float q7 = __shfl(a7, gbase + m, 64);
        int rb = (8 * m) * 16 + 2 * l;
        float4 w;
        w = Ws4[rb];            o0.x += q0*w.x; o0.y += q0*w.y; o0.z += q0*w.z; o0.w += q0*w.w;
        w = Ws4[rb + 1];        o1.x += q0*w.x; o1.y += q0*w.y; o1.z += q0*w.z; o1.w += q0*w.w;
        w = Ws4[rb + 16];       o0.x += q1*w.x; o0.y += q1*w.y; o0.z += q1*w.z; o0.w += q1*w.w;
        w = Ws4[rb + 17];       o1.x += q1*w.x; o1.y += q1*w.y; o1.z += q1*w.z; o1.w += q1*w.w;
        w = Ws4[rb + 32];       o0.x += q2*w.x; o0.y += q2*w.y; o0.z += q2*w.z; o0.w += q2*w.w;
        w = Ws4[rb + 33];       o1.x += q2*w.x; o1.y += q2*w.y; o1.z += q2*w.z; o1.w += q2*w.w;
        w = Ws4[rb + 48];       o0.x += q3*w.x; o0.y += q3*w.y; o0.z += q3*w.z; o0.w += q3*w.w;
        w = Ws4[rb + 49];       o1.x += q3*w.x; o1.y += q3*w.y; o1.z += q3*w.z; o1.w += q3*w.w;
        w = Ws4[rb + 64];       o0.x += q4*w.x; o0.y += q4*w.y; o0.z += q4*w.z; o0.w += q4*w.w;
        w = Ws4[rb + 65];       o1.x += q4*w.x; o1.y += q4*w.y; o1.z += q4*w.z; o1.w += q4*w.w;
        w = Ws4[rb + 80];       o0.x += q5*w.x; o0.y += q5*w.y; o0.z += q5*w.z; o0.w += q5*w.w;
        w = Ws4[rb + 81];       o1.x += q5*w.x; o1.y += q5*w.y; o1.z += q5*w.z; o1.w += q5*w.w;
        w = Ws4[rb + 96];       o0.x += q6*w.x; o0.y += q6*w.y; o0.z += q6*w.z; o0.w += q6*w.w;
        w = Ws4[rb + 97];       o1.x += q6*w.x; o1.y += q6*w.y; o1.z += q6*w.z; o1.w += q6*w.w;
        w = Ws4[rb + 112];      o0.x += q7*w.x; o0.y += q7*w.y; o0.z += q7*w.z; o0.w += q7*w.w;
        w = Ws4[rb + 113];      o1.x += q7*w.x; o1.y += q7*w.y; o1.z += q7*w.z; o1.w += q7*w.w;
    }
    if (SCALE_OUT) {
        float ro = rs_out[node];
        o0.x = (o0.x < 0.f ? 0.f : o0.x) * ro;
        o0.y = (o0.y < 0.f ? 0.f : o0.y) * ro;
        o0.z = (o0.z < 0.f ? 0.f : o0.z) * ro;
        o0.w = (o0.w < 0.f ? 0.f : o0.w) * ro;
        o1.x = (o1.x < 0.f ? 0.f : o1.x) * ro;
        o1.y = (o1.y < 0.f ? 0.f : o1.y) * ro;
        o1.z = (o1.z < 0.f ? 0.f : o1.z) * ro;
        o1.w = (o1.w < 0.f ? 0.f : o1.w) * ro;
        uint4 ho;
        *(__half2*)&ho.x = __float22half2_rn(make_float2(o0.x, o0.y));
        *(__half2*)&ho.y = __float22half2_rn(make_float2(o0.z, o0.w));
        *(__half2*)&ho.z = __float22half2_rn(make_float2(o1.x, o1.y));
        *(__half2*)&ho.w = __float22half2_rn(make_float2(o1.z, o1.w));
        ((uint4*)outp)[node * 8 + l] = ho;             // fp16 next-layer table
    } else {
        float4* o4 = (float4*)outp;
        o4[node * 16 + 2 * l]     = o0;                // fp32 final output
        o4[node * 16 + 2 * l + 1] = o1;
    }
}

extern "C" void kernel_launch(void* const* d_in, const int* in_sizes, int n_in,
                              void* d_out, int out_size, void* d_ws, size_t ws_size,
                              hipStream_t stream) {
    const float* x   = (const float*)d_in[0];
    const int*   ei  = (const int*)d_in[1];
    const int*   src = ei;
    const int*   dst = ei + N_EDGES;
    const float* W1 = (const float*)d_in[3];
    const float* b1 = (const float*)d_in[4];
    const float* W2 = (const float*)d_in[5];
    const float* b2 = (const float*)d_in[6];
    const float* W3 = (const float*)d_in[7];
    const float* b3 = (const float*)d_in[8];
    float* out = (float*)d_out;

    // workspace (~28.3 MB): R23 layout, 'so' slot reused as lscan, + rowtot.
    char* ws = (char*)d_ws;
    float* rs        = (float*)ws;                                 // [2N]
    float* rs_out    = rs;
    float* rs_in     = rs + N_NODES;
    int*   row_start = (int*)(rs + 2 * N_NODES);                   // [N+256]
    int*   block_h   = row_start + (N_NODES + 256);                // [65536]
    int*   lscan     = block_h + 256 * CHUNKS;                     // [65536]
    unsigned short* csr_src = (unsigned short*)(lscan + 256 * CHUNKS);// [E+16]
    h4*    bufA      = (h4*)(csr_src + N_EDGES + 16);              // [(N+1)*16]
    h4*    bufB      = bufA + (size_t)(N_NODES + 1) * 16;          // [(N+1)*16]
    unsigned* partial = (unsigned*)(bufB + (size_t)(N_NODES + 1) * 16); // 8 MB
    int*   rowtot    = (int*)(partial + (size_t)HB * OH_WORDS);    // [256]
    int*   bpack     = (int*)bufB;                                 // 4 MB alias
    uint2* zeroA     = (uint2*)(bufA + (size_t)N_NODES * 16);      // row N_NODES
    uint2* zeroB     = (uint2*)(bufB + (size_t)N_NODES * 16);

    const int fb = N_NODES / 32;      // 2048 blocks (8 nodes/wave x 4 waves)

    edge_hist    <<<HB, 256, 0, stream>>>(src, dst, block_h, partial, zeroA, zeroB);
    scan_oh2p    <<<256, 256, 0, stream>>>(block_h, lscan, rowtot, partial, rs_out,
                                           (const float4*)x, bufA);
    part_scatter <<<CHUNKS, 256, 0, stream>>>(src, dst, lscan, rowtot, bpack);
    bucket_fused <<<256, 256, 0, stream>>>(bpack, rowtot, row_start, rs_in, csr_src);

    // layers: bufA -> bufB(fp16, scaled) -> bufA(fp16, scaled) -> d_out (fp32)
    fused_layer<true ><<<fb, 256, 0, stream>>>((const uint4*)bufA, row_start, csr_src, rs_out, rs_in, W1, b1, (void*)bufB);
    fused_layer<true ><<<fb, 256, 0, stream>>>((const uint4*)bufB, row_start, csr_src, rs_out, rs_in, W2, b2, (void*)bufA);
    fused_layer<false><<<fb, 256, 0, stream>>>((const uint4*)bufA, row_start, csr_src, rs_out, rs_in, W3, b3, (void*)out);
}